// Round 1
// baseline (1377.245 us; speedup 1.0000x reference)
//
#include <hip/hip_runtime.h>

// GAT 3-layer forward, MI355X. Strategy:
//  - CSR-by-dst built on device each call (hist + scan + scatter), no float atomics.
//  - wave-per-node aggregation: pass1 max (8 edges x 8 heads per iter), pass2
//    edge-serial with lane=feature (coalesced 256B h[src] row gathers).
//  - layer2: aggregate h1 per head (g=[N,8,64]) then GEMM with rearranged W2
//    (mean-over-heads folded in). Avoids [N,320] gathers.
// ws requirement ~271 MB.

#define NNODE 100000
#define NEDGE 1600000
#define ETOT  (NNODE + NEDGE)   // 1,700,000 incl self-loops
#define FIN   512
#define HID   64
#define NHEAD 8
#define NCLS  40

static __device__ __forceinline__ float lrelu(float x) { return x > 0.f ? x : 0.2f * x; }

// ---------------- CSR build ----------------
__global__ __launch_bounds__(256) void k_hist(const int* __restrict__ ei, int* __restrict__ deg) {
    int e = blockIdx.x * 256 + threadIdx.x;
    if (e >= ETOT) return;
    int dst = (e < NEDGE) ? ei[NEDGE + e] : (e - NEDGE);
    atomicAdd(&deg[dst], 1);
}

__global__ __launch_bounds__(256) void k_scan1(const int* __restrict__ deg, int* __restrict__ rowptr,
                                               int* __restrict__ bsum) {
    __shared__ int sm[256];
    int b = blockIdx.x, t = threadIdx.x;
    int base = b * 1024 + t * 4;
    int v0=0,v1=0,v2=0,v3=0;
    if (base + 0 < NNODE) v0 = deg[base + 0];
    if (base + 1 < NNODE) v1 = deg[base + 1];
    if (base + 2 < NNODE) v2 = deg[base + 2];
    if (base + 3 < NNODE) v3 = deg[base + 3];
    int tsum = v0 + v1 + v2 + v3;
    sm[t] = tsum;
    __syncthreads();
    int val = tsum;
    for (int off = 1; off < 256; off <<= 1) {
        int y = (t >= off) ? sm[t - off] : 0;
        __syncthreads();
        val += y;
        sm[t] = val;
        __syncthreads();
    }
    int ex = val - tsum;
    if (base + 0 < NNODE) rowptr[base + 0] = ex;
    if (base + 1 < NNODE) rowptr[base + 1] = ex + v0;
    if (base + 2 < NNODE) rowptr[base + 2] = ex + v0 + v1;
    if (base + 3 < NNODE) rowptr[base + 3] = ex + v0 + v1 + v2;
    if (t == 255) bsum[b] = val;
}

__global__ __launch_bounds__(256) void k_scan2(int* __restrict__ bsum, int nb) {
    __shared__ int sm[256];
    int t = threadIdx.x;
    int v = (t < nb) ? bsum[t] : 0;
    sm[t] = v;
    __syncthreads();
    int val = v;
    for (int off = 1; off < 256; off <<= 1) {
        int y = (t >= off) ? sm[t - off] : 0;
        __syncthreads();
        val += y;
        sm[t] = val;
        __syncthreads();
    }
    if (t < nb) bsum[t] = val - v;
}

__global__ __launch_bounds__(256) void k_scan3(int* __restrict__ rowptr, const int* __restrict__ bsum) {
    int i = blockIdx.x * 256 + threadIdx.x;
    if (i < NNODE) rowptr[i] += bsum[i >> 10];
    if (i == 0) rowptr[NNODE] = ETOT;
}

__global__ __launch_bounds__(256) void k_scatter(const int* __restrict__ ei, const int* __restrict__ rowptr,
                                                 int* __restrict__ fill, int* __restrict__ csr) {
    int e = blockIdx.x * 256 + threadIdx.x;
    if (e >= ETOT) return;
    int s, d;
    if (e < NEDGE) { s = ei[e]; d = ei[NEDGE + e]; } else { s = e - NEDGE; d = s; }
    int pos = rowptr[d] + atomicAdd(&fill[d], 1);
    csr[pos] = s;
}

// ---------------- generic fp32 GEMM: C[NrowsxNC] = A[NrowsxK] @ B[KxNC] ----------------
// block = 64 rows x 64 cols, 256 threads, 4x4 register tile, K-chunks of 32.
__global__ __launch_bounds__(256) void k_gemm(const float* __restrict__ A, const float* __restrict__ B,
                                              float* __restrict__ C, int Nrows, int K, int NC) {
    __shared__ float As[32][68];   // transposed [kk][row], pad for banks + float4 align
    __shared__ float Bs[32][64];
    int r0 = blockIdx.x * 64;
    int c0 = blockIdx.y * 64;
    int t = threadIdx.x;
    int tx = t & 15, ty = t >> 4;
    float acc[4][4];
    #pragma unroll
    for (int i = 0; i < 4; ++i)
        #pragma unroll
        for (int j = 0; j < 4; ++j) acc[i][j] = 0.f;

    for (int k0 = 0; k0 < K; k0 += 32) {
        // stage A (64 rows x 32 k), transposed into As[kk][row]
        int j = t * 4;
        #pragma unroll
        for (int p = 0; p < 2; ++p) {
            int row = j >> 5, kk = j & 31;
            float4 v = make_float4(0.f, 0.f, 0.f, 0.f);
            int gr = r0 + row;
            if (gr < Nrows) v = *(const float4*)&A[gr * K + k0 + kk];
            As[kk + 0][row] = v.x; As[kk + 1][row] = v.y;
            As[kk + 2][row] = v.z; As[kk + 3][row] = v.w;
            j += 1024;
        }
        // stage B (32 k x 64 cols)
        j = t * 4;
        #pragma unroll
        for (int p = 0; p < 2; ++p) {
            int row = j >> 6, col = j & 63;
            float4 w = make_float4(0.f, 0.f, 0.f, 0.f);
            if (c0 + col < NC) w = *(const float4*)&B[(k0 + row) * NC + c0 + col];
            *(float4*)&Bs[row][col] = w;
            j += 1024;
        }
        __syncthreads();
        #pragma unroll
        for (int kk = 0; kk < 32; ++kk) {
            float4 a = *(const float4*)&As[kk][ty * 4];
            float4 b = *(const float4*)&Bs[kk][tx * 4];
            acc[0][0] = fmaf(a.x, b.x, acc[0][0]); acc[0][1] = fmaf(a.x, b.y, acc[0][1]);
            acc[0][2] = fmaf(a.x, b.z, acc[0][2]); acc[0][3] = fmaf(a.x, b.w, acc[0][3]);
            acc[1][0] = fmaf(a.y, b.x, acc[1][0]); acc[1][1] = fmaf(a.y, b.y, acc[1][1]);
            acc[1][2] = fmaf(a.y, b.z, acc[1][2]); acc[1][3] = fmaf(a.y, b.w, acc[1][3]);
            acc[2][0] = fmaf(a.z, b.x, acc[2][0]); acc[2][1] = fmaf(a.z, b.y, acc[2][1]);
            acc[2][2] = fmaf(a.z, b.z, acc[2][2]); acc[2][3] = fmaf(a.z, b.w, acc[2][3]);
            acc[3][0] = fmaf(a.w, b.x, acc[3][0]); acc[3][1] = fmaf(a.w, b.y, acc[3][1]);
            acc[3][2] = fmaf(a.w, b.z, acc[3][2]); acc[3][3] = fmaf(a.w, b.w, acc[3][3]);
        }
        __syncthreads();
    }
    #pragma unroll
    for (int i = 0; i < 4; ++i) {
        int gr = r0 + ty * 4 + i;
        if (gr < Nrows && (c0 + tx * 4) < NC) {
            float4 o = make_float4(acc[i][0], acc[i][1], acc[i][2], acc[i][3]);
            *(float4*)&C[gr * NC + c0 + tx * 4] = o;
        }
    }
}

// ---------------- alpha for head-sliced features (layers 0/1, C=8) ----------------
// wave per node; lane = h*8+c; a_s/a_d flat [64].
__global__ __launch_bounds__(256) void k_alpha_hs(const float* __restrict__ h, const float* __restrict__ a_s,
                                                  const float* __restrict__ a_d,
                                                  float* __restrict__ asrc, float* __restrict__ adst) {
    int t = threadIdx.x;
    int lane = t & 63;
    int n = (blockIdx.x * 256 + t) >> 6;
    if (n >= NNODE) return;
    float v = h[n * 64 + lane];
    float s = v * a_s[lane];
    float d = v * a_d[lane];
    s += __shfl_xor(s, 1); s += __shfl_xor(s, 2); s += __shfl_xor(s, 4);
    d += __shfl_xor(d, 1); d += __shfl_xor(d, 2); d += __shfl_xor(d, 4);
    if ((lane & 7) == 0) {
        asrc[n * 8 + (lane >> 3)] = s;
        adst[n * 8 + (lane >> 3)] = d;
    }
}

// ---------------- aggregation for layers 0/1 (64 features) ----------------
__global__ __launch_bounds__(256) void k_agg64(const float* __restrict__ h, const float* __restrict__ asrc,
                                               const float* __restrict__ adst, const int* __restrict__ rowptr,
                                               const int* __restrict__ csr, const float* __restrict__ bias,
                                               float* __restrict__ out, int doElu) {
    int t = threadIdx.x;
    int lane = t & 63;
    int n = (blockIdx.x * 256 + t) >> 6;
    if (n >= NNODE) return;
    int start = rowptr[n], end = rowptr[n + 1];
    int h_lo = lane & 7;         // head in pass-1 layout
    int h_hi = lane >> 3;        // head in feature layout (lane = h*8+c)
    float adst_lo = adst[n * 8 + h_lo];
    // pass 1: per-head max over incoming edges (8 edges x 8 heads per iter)
    float m = -1e30f;
    for (int i = start + (lane >> 3); i < end; i += 8) {
        int s = csr[i];
        m = fmaxf(m, lrelu(asrc[s * 8 + h_lo] + adst_lo));
    }
    m = fmaxf(m, __shfl_xor(m, 8));
    m = fmaxf(m, __shfl_xor(m, 16));
    m = fmaxf(m, __shfl_xor(m, 32));
    // remap to feature layout
    float m_hi    = __shfl(m, h_hi);
    float adst_hi = __shfl(adst_lo, h_hi);
    // pass 2: edge-serial accumulate
    float acc = 0.f, ssum = 0.f;
    for (int i = start; i < end; ++i) {
        int s = csr[i];
        float e = lrelu(asrc[s * 8 + h_hi] + adst_hi);
        float ex = __expf(e - m_hi);
        ssum += ex;
        acc = fmaf(ex, h[s * 64 + lane], acc);
    }
    float o = acc / (ssum + 1e-16f) + bias[lane];
    if (doElu) o = (o > 0.f) ? o : expm1f(o);
    out[n * 64 + lane] = o;
}

// ---------------- layer-2 weight precompute ----------------
// wa[which*512 + h*64 + k] = sum_c W2[k,h*40+c]*a2[h,c]   (which: 0=src,1=dst)
// w2r[(h*64+k)*40 + c]     = W2[k,h*40+c] * 0.125   (head-mean folded)
__global__ __launch_bounds__(256) void k_prep_w2(const float* __restrict__ W2, const float* __restrict__ as2,
                                                 const float* __restrict__ ad2,
                                                 float* __restrict__ wa, float* __restrict__ w2r) {
    int idx = blockIdx.x * 256 + threadIdx.x;
    if (idx < 1024) {
        int which = idx >> 9;
        int hh = (idx >> 6) & 7, k = idx & 63;
        const float* a = which ? ad2 : as2;
        float s = 0.f;
        #pragma unroll 8
        for (int c = 0; c < NCLS; ++c) s += W2[k * 320 + hh * 40 + c] * a[hh * 40 + c];
        wa[idx] = s;
    }
    for (int j2 = idx; j2 < 512 * NCLS; j2 += gridDim.x * 256) {
        int rc = j2 / NCLS, c = j2 - rc * NCLS;
        int hh = rc >> 6, k = rc & 63;
        w2r[j2] = W2[k * 320 + hh * 40 + c] * 0.125f;
    }
}

// ---------------- alpha for layer 2 (via h1 and pre-contracted wa) ----------------
__global__ __launch_bounds__(256) void k_alpha2(const float* __restrict__ h, const float* __restrict__ wa,
                                                float* __restrict__ asrc, float* __restrict__ adst) {
    __shared__ float ws[1024];
    int t = threadIdx.x;
    for (int j = t; j < 1024; j += 256) ws[j] = wa[j];
    __syncthreads();
    int lane = t & 63;
    int n = (blockIdx.x * 256 + t) >> 6;
    if (n >= NNODE) return;
    float v = h[n * 64 + lane];
    #pragma unroll
    for (int hh = 0; hh < 8; ++hh) {
        float s = v * ws[hh * 64 + lane];
        float d = v * ws[512 + hh * 64 + lane];
        #pragma unroll
        for (int mk = 32; mk; mk >>= 1) { s += __shfl_xor(s, mk); d += __shfl_xor(d, mk); }
        if (lane == 0) { asrc[n * 8 + hh] = s; adst[n * 8 + hh] = d; }
    }
}

// ---------------- layer-2 aggregation: g[n, h*64+k] = sum_e alpha[e,h]*h1[src,k] ----------------
__global__ __launch_bounds__(256) void k_agg512(const float* __restrict__ h, const float* __restrict__ asrc,
                                                const float* __restrict__ adst, const int* __restrict__ rowptr,
                                                const int* __restrict__ csr, float* __restrict__ g) {
    int t = threadIdx.x;
    int lane = t & 63;
    int n = (blockIdx.x * 256 + t) >> 6;
    if (n >= NNODE) return;
    int start = rowptr[n], end = rowptr[n + 1];
    int h_lo = lane & 7;
    float adst_lo = adst[n * 8 + h_lo];
    // pass 1: per-head max
    float m = -1e30f;
    for (int i = start + (lane >> 3); i < end; i += 8) {
        int s = csr[i];
        m = fmaxf(m, lrelu(asrc[s * 8 + h_lo] + adst_lo));
    }
    m = fmaxf(m, __shfl_xor(m, 8));
    m = fmaxf(m, __shfl_xor(m, 16));
    m = fmaxf(m, __shfl_xor(m, 32));
    // pass 2: edge-serial; lane's ex is for head lane&7; broadcast across heads
    float acc[8];
    #pragma unroll
    for (int hh = 0; hh < 8; ++hh) acc[hh] = 0.f;
    float ssum = 0.f;
    for (int i = start; i < end; ++i) {
        int s = csr[i];
        float e = lrelu(asrc[s * 8 + h_lo] + adst_lo);
        float ex = __expf(e - m);
        ssum += ex;
        float v = h[s * 64 + lane];
        #pragma unroll
        for (int hh = 0; hh < 8; ++hh) {
            float exh = __shfl(ex, hh);   // lane hh holds head hh's ex
            acc[hh] = fmaf(exh, v, acc[hh]);
        }
    }
    #pragma unroll
    for (int hh = 0; hh < 8; ++hh) {
        float sh = __shfl(ssum, hh);
        g[n * 512 + hh * 64 + lane] = acc[hh] / (sh + 1e-16f);
    }
}

// ---------------- final: bias + log_softmax in place on d_out [N,40] ----------------
__global__ __launch_bounds__(256) void k_logsm(float* __restrict__ out, const float* __restrict__ b2) {
    int t = threadIdx.x;
    int lane = t & 63;
    int n = (blockIdx.x * 256 + t) >> 6;
    if (n >= NNODE) return;
    float v = (lane < NCLS) ? out[n * NCLS + lane] + b2[lane] : -1e30f;
    float m = v;
    #pragma unroll
    for (int mk = 32; mk; mk >>= 1) m = fmaxf(m, __shfl_xor(m, mk));
    float ex = (lane < NCLS) ? __expf(v - m) : 0.f;
    float s = ex;
    #pragma unroll
    for (int mk = 32; mk; mk >>= 1) s += __shfl_xor(s, mk);
    float r = v - m - logf(s);
    if (lane < NCLS) out[n * NCLS + lane] = r;
}

// ---------------- launch ----------------
extern "C" void kernel_launch(void* const* d_in, const int* in_sizes, int n_in,
                              void* d_out, int out_size, void* d_ws, size_t ws_size,
                              hipStream_t stream) {
    (void)in_sizes; (void)n_in; (void)out_size; (void)ws_size;
    const float* x   = (const float*)d_in[0];
    const int*   ei  = (const int*)d_in[1];
    const float* W0  = (const float*)d_in[2];
    const float* as0 = (const float*)d_in[3];
    const float* ad0 = (const float*)d_in[4];
    const float* b0  = (const float*)d_in[5];
    const float* W1  = (const float*)d_in[6];
    const float* as1 = (const float*)d_in[7];
    const float* ad1 = (const float*)d_in[8];
    const float* b1  = (const float*)d_in[9];
    const float* W2  = (const float*)d_in[10];
    const float* as2 = (const float*)d_in[11];
    const float* ad2 = (const float*)d_in[12];
    const float* b2  = (const float*)d_in[13];
    float* outp = (float*)d_out;

    // workspace layout (256B aligned)
    size_t off = 0;
    auto alloc = [&](size_t bytes) -> void* {
        void* p = (char*)d_ws + off;
        off += (bytes + 255) & ~(size_t)255;
        return p;
    };
    int*   deg    = (int*)alloc((size_t)NNODE * 4);
    int*   fill   = (int*)alloc((size_t)NNODE * 4);
    int*   rowptr = (int*)alloc((size_t)(NNODE + 1) * 4);
    int*   bsum   = (int*)alloc(256 * 4);
    int*   csr    = (int*)alloc((size_t)ETOT * 4);
    float* asrc   = (float*)alloc((size_t)NNODE * 8 * 4);
    float* adst   = (float*)alloc((size_t)NNODE * 8 * 4);
    float* bufA   = (float*)alloc((size_t)NNODE * 64 * 4);
    float* bufB   = (float*)alloc((size_t)NNODE * 64 * 4);
    float* wa     = (float*)alloc(1024 * 4);
    float* w2r    = (float*)alloc((size_t)512 * NCLS * 4);
    float* g      = (float*)alloc((size_t)NNODE * 512 * 4);

    const int nb = (NNODE + 1023) / 1024;          // 98
    const int egrid = (ETOT + 255) / 256;          // 6641
    const int ngrid = (NNODE + 255) / 256;         // 391
    const int wgrid = NNODE / 4;                   // 25000 (wave per node, 4 waves/block)
    const int rtiles = (NNODE + 63) / 64;          // 1563

    // CSR build
    hipMemsetAsync(deg, 0, (size_t)NNODE * 4, stream);
    hipMemsetAsync(fill, 0, (size_t)NNODE * 4, stream);
    k_hist<<<egrid, 256, 0, stream>>>(ei, deg);
    k_scan1<<<nb, 256, 0, stream>>>(deg, rowptr, bsum);
    k_scan2<<<1, 256, 0, stream>>>(bsum, nb);
    k_scan3<<<ngrid, 256, 0, stream>>>(rowptr, bsum);
    k_scatter<<<egrid, 256, 0, stream>>>(ei, rowptr, fill, csr);

    // layer 0
    k_gemm<<<dim3(rtiles, 1), 256, 0, stream>>>(x, W0, bufA, NNODE, FIN, HID);
    k_alpha_hs<<<wgrid, 256, 0, stream>>>(bufA, as0, ad0, asrc, adst);
    k_agg64<<<wgrid, 256, 0, stream>>>(bufA, asrc, adst, rowptr, csr, b0, bufB, 1);

    // layer 1
    k_gemm<<<dim3(rtiles, 1), 256, 0, stream>>>(bufB, W1, bufA, NNODE, HID, HID);
    k_alpha_hs<<<wgrid, 256, 0, stream>>>(bufA, as1, ad1, asrc, adst);
    k_agg64<<<wgrid, 256, 0, stream>>>(bufA, asrc, adst, rowptr, csr, b1, bufB, 1);

    // layer 2 (aggregate-then-transform)
    k_prep_w2<<<80, 256, 0, stream>>>(W2, as2, ad2, wa, w2r);
    k_alpha2<<<wgrid, 256, 0, stream>>>(bufB, wa, asrc, adst);
    k_agg512<<<wgrid, 256, 0, stream>>>(bufB, asrc, adst, rowptr, csr, g);
    k_gemm<<<dim3(rtiles, 1), 256, 0, stream>>>(g, w2r, outp, NNODE, 512, NCLS);
    k_logsm<<<wgrid, 256, 0, stream>>>(outp, b2);
}

// Round 3
// 1225.228 us; speedup vs baseline: 1.1241x; 1.1241x over previous
//
#include <hip/hip_runtime.h>

// GAT 3-layer forward, MI355X. Round 2 resubmit (round-2 bench never acquired a GPU):
//  - CSR-by-dst built on device each call (hist + scan + scatter), no float atomics.
//  - wave-per-node aggregation with readfirstlane-scalarized csr/rowptr and a
//    depth-3 software pipeline (2 gathers + 3 csr reads in flight) to hide
//    L2/L3 gather latency (round-1: VALUBusy 46%, half the time stalled).
//  - layer2: aggregate h1 per head (g=[N,8,64]) then GEMM with rearranged W2.

#define NNODE 100000
#define NEDGE 1600000
#define ETOT  (NNODE + NEDGE)   // 1,700,000 incl self-loops
#define FIN   512
#define HID   64
#define NHEAD 8
#define NCLS  40

static __device__ __forceinline__ float lrelu(float x) { return x > 0.f ? x : 0.2f * x; }
static __device__ __forceinline__ int rfl(int v) { return __builtin_amdgcn_readfirstlane(v); }

// ---------------- CSR build ----------------
__global__ __launch_bounds__(256) void k_hist(const int* __restrict__ ei, int* __restrict__ deg) {
    int e = blockIdx.x * 256 + threadIdx.x;
    if (e >= ETOT) return;
    int dst = (e < NEDGE) ? ei[NEDGE + e] : (e - NEDGE);
    atomicAdd(&deg[dst], 1);
}

__global__ __launch_bounds__(256) void k_scan1(const int* __restrict__ deg, int* __restrict__ rowptr,
                                               int* __restrict__ bsum) {
    __shared__ int sm[256];
    int b = blockIdx.x, t = threadIdx.x;
    int base = b * 1024 + t * 4;
    int v0=0,v1=0,v2=0,v3=0;
    if (base + 0 < NNODE) v0 = deg[base + 0];
    if (base + 1 < NNODE) v1 = deg[base + 1];
    if (base + 2 < NNODE) v2 = deg[base + 2];
    if (base + 3 < NNODE) v3 = deg[base + 3];
    int tsum = v0 + v1 + v2 + v3;
    sm[t] = tsum;
    __syncthreads();
    int val = tsum;
    for (int off = 1; off < 256; off <<= 1) {
        int y = (t >= off) ? sm[t - off] : 0;
        __syncthreads();
        val += y;
        sm[t] = val;
        __syncthreads();
    }
    int ex = val - tsum;
    if (base + 0 < NNODE) rowptr[base + 0] = ex;
    if (base + 1 < NNODE) rowptr[base + 1] = ex + v0;
    if (base + 2 < NNODE) rowptr[base + 2] = ex + v0 + v1;
    if (base + 3 < NNODE) rowptr[base + 3] = ex + v0 + v1 + v2;
    if (t == 255) bsum[b] = val;
}

__global__ __launch_bounds__(256) void k_scan2(int* __restrict__ bsum, int nb) {
    __shared__ int sm[256];
    int t = threadIdx.x;
    int v = (t < nb) ? bsum[t] : 0;
    sm[t] = v;
    __syncthreads();
    int val = v;
    for (int off = 1; off < 256; off <<= 1) {
        int y = (t >= off) ? sm[t - off] : 0;
        __syncthreads();
        val += y;
        sm[t] = val;
        __syncthreads();
    }
    if (t < nb) bsum[t] = val - v;
}

__global__ __launch_bounds__(256) void k_scan3(int* __restrict__ rowptr, const int* __restrict__ bsum) {
    int i = blockIdx.x * 256 + threadIdx.x;
    if (i < NNODE) rowptr[i] += bsum[i >> 10];
    if (i == 0) rowptr[NNODE] = ETOT;
}

__global__ __launch_bounds__(256) void k_scatter(const int* __restrict__ ei, const int* __restrict__ rowptr,
                                                 int* __restrict__ fill, int* __restrict__ csr) {
    int e = blockIdx.x * 256 + threadIdx.x;
    if (e >= ETOT) return;
    int s, d;
    if (e < NEDGE) { s = ei[e]; d = ei[NEDGE + e]; } else { s = e - NEDGE; d = s; }
    int pos = rowptr[d] + atomicAdd(&fill[d], 1);
    csr[pos] = s;
}

// ---------------- generic fp32 GEMM: C[NrowsxNC] = A[NrowsxK] @ B[KxNC] ----------------
__global__ __launch_bounds__(256) void k_gemm(const float* __restrict__ A, const float* __restrict__ B,
                                              float* __restrict__ C, int Nrows, int K, int NC) {
    __shared__ float As[32][68];
    __shared__ float Bs[32][64];
    int r0 = blockIdx.x * 64;
    int c0 = blockIdx.y * 64;
    int t = threadIdx.x;
    int tx = t & 15, ty = t >> 4;
    float acc[4][4];
    #pragma unroll
    for (int i = 0; i < 4; ++i)
        #pragma unroll
        for (int j = 0; j < 4; ++j) acc[i][j] = 0.f;

    for (int k0 = 0; k0 < K; k0 += 32) {
        int j = t * 4;
        #pragma unroll
        for (int p = 0; p < 2; ++p) {
            int row = j >> 5, kk = j & 31;
            float4 v = make_float4(0.f, 0.f, 0.f, 0.f);
            int gr = r0 + row;
            if (gr < Nrows) v = *(const float4*)&A[gr * K + k0 + kk];
            As[kk + 0][row] = v.x; As[kk + 1][row] = v.y;
            As[kk + 2][row] = v.z; As[kk + 3][row] = v.w;
            j += 1024;
        }
        j = t * 4;
        #pragma unroll
        for (int p = 0; p < 2; ++p) {
            int row = j >> 6, col = j & 63;
            float4 w = make_float4(0.f, 0.f, 0.f, 0.f);
            if (c0 + col < NC) w = *(const float4*)&B[(k0 + row) * NC + c0 + col];
            *(float4*)&Bs[row][col] = w;
            j += 1024;
        }
        __syncthreads();
        #pragma unroll
        for (int kk = 0; kk < 32; ++kk) {
            float4 a = *(const float4*)&As[kk][ty * 4];
            float4 b = *(const float4*)&Bs[kk][tx * 4];
            acc[0][0] = fmaf(a.x, b.x, acc[0][0]); acc[0][1] = fmaf(a.x, b.y, acc[0][1]);
            acc[0][2] = fmaf(a.x, b.z, acc[0][2]); acc[0][3] = fmaf(a.x, b.w, acc[0][3]);
            acc[1][0] = fmaf(a.y, b.x, acc[1][0]); acc[1][1] = fmaf(a.y, b.y, acc[1][1]);
            acc[1][2] = fmaf(a.y, b.z, acc[1][2]); acc[1][3] = fmaf(a.y, b.w, acc[1][3]);
            acc[2][0] = fmaf(a.z, b.x, acc[2][0]); acc[2][1] = fmaf(a.z, b.y, acc[2][1]);
            acc[2][2] = fmaf(a.z, b.z, acc[2][2]); acc[2][3] = fmaf(a.z, b.w, acc[2][3]);
            acc[3][0] = fmaf(a.w, b.x, acc[3][0]); acc[3][1] = fmaf(a.w, b.y, acc[3][1]);
            acc[3][2] = fmaf(a.w, b.z, acc[3][2]); acc[3][3] = fmaf(a.w, b.w, acc[3][3]);
        }
        __syncthreads();
    }
    #pragma unroll
    for (int i = 0; i < 4; ++i) {
        int gr = r0 + ty * 4 + i;
        if (gr < Nrows && (c0 + tx * 4) < NC) {
            float4 o = make_float4(acc[i][0], acc[i][1], acc[i][2], acc[i][3]);
            *(float4*)&C[gr * NC + c0 + tx * 4] = o;
        }
    }
}

// ---------------- alpha for head-sliced features (layers 0/1) ----------------
__global__ __launch_bounds__(256) void k_alpha_hs(const float* __restrict__ h, const float* __restrict__ a_s,
                                                  const float* __restrict__ a_d,
                                                  float* __restrict__ asrc, float* __restrict__ adst) {
    int t = threadIdx.x;
    int lane = t & 63;
    int n = (blockIdx.x * 256 + t) >> 6;
    if (n >= NNODE) return;
    float v = h[n * 64 + lane];
    float s = v * a_s[lane];
    float d = v * a_d[lane];
    s += __shfl_xor(s, 1); s += __shfl_xor(s, 2); s += __shfl_xor(s, 4);
    d += __shfl_xor(d, 1); d += __shfl_xor(d, 2); d += __shfl_xor(d, 4);
    if ((lane & 7) == 0) {
        asrc[n * 8 + (lane >> 3)] = s;
        adst[n * 8 + (lane >> 3)] = d;
    }
}

// ---------------- aggregation for layers 0/1 (64 features), pipelined ----------------
__global__ __launch_bounds__(256) void k_agg64(const float* __restrict__ h, const float* __restrict__ asrc,
                                               const float* __restrict__ adst, const int* __restrict__ rowptr,
                                               const int* __restrict__ csr, const float* __restrict__ bias,
                                               float* __restrict__ out, int doElu) {
    int t = threadIdx.x;
    int lane = t & 63;
    int n = (blockIdx.x * 256 + t) >> 6;
    if (n >= NNODE) return;
    int start = rfl(rowptr[n]);
    int end   = rfl(rowptr[n + 1]);
    int h_lo = lane & 7;
    int h_hi = lane >> 3;
    float adst_lo = adst[n * 8 + h_lo];
    // pass 1: per-head max, 8 edges x 8 heads per iter, 2 loads in flight
    float m = -1e30f;
    for (int i = start + (lane >> 3); i < end; i += 16) {
        int s0 = csr[i];
        int i2 = i + 8;
        int s1 = (i2 < end) ? csr[i2] : s0;
        float a0 = asrc[s0 * 8 + h_lo];
        float a1 = asrc[s1 * 8 + h_lo];
        m = fmaxf(m, lrelu(a0 + adst_lo));
        if (i2 < end) m = fmaxf(m, lrelu(a1 + adst_lo));
    }
    m = fmaxf(m, __shfl_xor(m, 8));
    m = fmaxf(m, __shfl_xor(m, 16));
    m = fmaxf(m, __shfl_xor(m, 32));
    float m_hi    = __shfl(m, h_hi);
    float adst_hi = __shfl(adst_lo, h_hi);
    // pass 2: edge-serial, depth-3 pipeline (sA/sB/sC in SGPRs, 2 gathers in flight)
    float acc = 0.f, ssum = 0.f;
    int i1 = min(start + 1, end - 1);
    int i2p = min(start + 2, end - 1);
    int sA = rfl(csr[start]);
    int sB = rfl(csr[i1]);
    int sC = rfl(csr[i2p]);
    float vA = h[sA * 64 + lane];
    float aA = asrc[sA * 8 + h_hi];
    float vB = h[sB * 64 + lane];
    float aB = asrc[sB * 8 + h_hi];
    for (int i = start; i < end; ++i) {
        int sN = (i + 3 < end) ? rfl(csr[i + 3]) : sC;
        float e = lrelu(aA + adst_hi);
        float ex = __expf(e - m_hi);
        ssum += ex;
        acc = fmaf(ex, vA, acc);
        vA = vB; aA = aB;
        vB = h[sC * 64 + lane];
        aB = asrc[sC * 8 + h_hi];
        sC = sN;
    }
    float o = acc / (ssum + 1e-16f) + bias[lane];
    if (doElu) o = (o > 0.f) ? o : expm1f(o);
    out[n * 64 + lane] = o;
}

// ---------------- layer-2 weight precompute ----------------
__global__ __launch_bounds__(256) void k_prep_w2(const float* __restrict__ W2, const float* __restrict__ as2,
                                                 const float* __restrict__ ad2,
                                                 float* __restrict__ wa, float* __restrict__ w2r) {
    int idx = blockIdx.x * 256 + threadIdx.x;
    if (idx < 1024) {
        int which = idx >> 9;
        int hh = (idx >> 6) & 7, k = idx & 63;
        const float* a = which ? ad2 : as2;
        float s = 0.f;
        #pragma unroll 8
        for (int c = 0; c < NCLS; ++c) s += W2[k * 320 + hh * 40 + c] * a[hh * 40 + c];
        wa[idx] = s;
    }
    for (int j2 = idx; j2 < 512 * NCLS; j2 += gridDim.x * 256) {
        int rc = j2 / NCLS, c = j2 - rc * NCLS;
        int hh = rc >> 6, k = rc & 63;
        w2r[j2] = W2[k * 320 + hh * 40 + c] * 0.125f;
    }
}

// ---------------- alpha for layer 2 ----------------
__global__ __launch_bounds__(256) void k_alpha2(const float* __restrict__ h, const float* __restrict__ wa,
                                                float* __restrict__ asrc, float* __restrict__ adst) {
    __shared__ float ws[1024];
    int t = threadIdx.x;
    for (int j = t; j < 1024; j += 256) ws[j] = wa[j];
    __syncthreads();
    int lane = t & 63;
    int n = (blockIdx.x * 256 + t) >> 6;
    if (n >= NNODE) return;
    float v = h[n * 64 + lane];
    #pragma unroll
    for (int hh = 0; hh < 8; ++hh) {
        float s = v * ws[hh * 64 + lane];
        float d = v * ws[512 + hh * 64 + lane];
        #pragma unroll
        for (int mk = 32; mk; mk >>= 1) { s += __shfl_xor(s, mk); d += __shfl_xor(d, mk); }
        if (lane == 0) { asrc[n * 8 + hh] = s; adst[n * 8 + hh] = d; }
    }
}

// ---------------- layer-2 aggregation, pipelined ----------------
__global__ __launch_bounds__(256) void k_agg512(const float* __restrict__ h, const float* __restrict__ asrc,
                                                const float* __restrict__ adst, const int* __restrict__ rowptr,
                                                const int* __restrict__ csr, float* __restrict__ g) {
    int t = threadIdx.x;
    int lane = t & 63;
    int n = (blockIdx.x * 256 + t) >> 6;
    if (n >= NNODE) return;
    int start = rfl(rowptr[n]);
    int end   = rfl(rowptr[n + 1]);
    int h_lo = lane & 7;
    float adst_lo = adst[n * 8 + h_lo];
    // pass 1: per-head max, 2 loads in flight
    float m = -1e30f;
    for (int i = start + (lane >> 3); i < end; i += 16) {
        int s0 = csr[i];
        int i2 = i + 8;
        int s1 = (i2 < end) ? csr[i2] : s0;
        float a0 = asrc[s0 * 8 + h_lo];
        float a1 = asrc[s1 * 8 + h_lo];
        m = fmaxf(m, lrelu(a0 + adst_lo));
        if (i2 < end) m = fmaxf(m, lrelu(a1 + adst_lo));
    }
    m = fmaxf(m, __shfl_xor(m, 8));
    m = fmaxf(m, __shfl_xor(m, 16));
    m = fmaxf(m, __shfl_xor(m, 32));
    // pass 2: edge-serial, depth-3 pipeline
    float acc[8];
    #pragma unroll
    for (int hh = 0; hh < 8; ++hh) acc[hh] = 0.f;
    float ssum = 0.f;
    int i1 = min(start + 1, end - 1);
    int i2p = min(start + 2, end - 1);
    int sA = rfl(csr[start]);
    int sB = rfl(csr[i1]);
    int sC = rfl(csr[i2p]);
    float vA = h[sA * 64 + lane];
    float aA = asrc[sA * 8 + h_lo];
    float vB = h[sB * 64 + lane];
    float aB = asrc[sB * 8 + h_lo];
    for (int i = start; i < end; ++i) {
        int sN = (i + 3 < end) ? rfl(csr[i + 3]) : sC;
        float e = lrelu(aA + adst_lo);
        float ex = __expf(e - m);
        ssum += ex;
        #pragma unroll
        for (int hh = 0; hh < 8; ++hh) {
            float exh = __shfl(ex, hh);
            acc[hh] = fmaf(exh, vA, acc[hh]);
        }
        vA = vB; aA = aB;
        vB = h[sC * 64 + lane];
        aB = asrc[sC * 8 + h_lo];
        sC = sN;
    }
    #pragma unroll
    for (int hh = 0; hh < 8; ++hh) {
        float sh = __shfl(ssum, hh);
        g[n * 512 + hh * 64 + lane] = acc[hh] / (sh + 1e-16f);
    }
}

// ---------------- final: bias + log_softmax in place on d_out [N,40] ----------------
__global__ __launch_bounds__(256) void k_logsm(float* __restrict__ out, const float* __restrict__ b2) {
    int t = threadIdx.x;
    int lane = t & 63;
    int n = (blockIdx.x * 256 + t) >> 6;
    if (n >= NNODE) return;
    float v = (lane < NCLS) ? out[n * NCLS + lane] + b2[lane] : -1e30f;
    float m = v;
    #pragma unroll
    for (int mk = 32; mk; mk >>= 1) m = fmaxf(m, __shfl_xor(m, mk));
    float ex = (lane < NCLS) ? __expf(v - m) : 0.f;
    float s = ex;
    #pragma unroll
    for (int mk = 32; mk; mk >>= 1) s += __shfl_xor(s, mk);
    float r = v - m - logf(s);
    if (lane < NCLS) out[n * NCLS + lane] = r;
}

// ---------------- launch ----------------
extern "C" void kernel_launch(void* const* d_in, const int* in_sizes, int n_in,
                              void* d_out, int out_size, void* d_ws, size_t ws_size,
                              hipStream_t stream) {
    (void)in_sizes; (void)n_in; (void)out_size; (void)ws_size;
    const float* x   = (const float*)d_in[0];
    const int*   ei  = (const int*)d_in[1];
    const float* W0  = (const float*)d_in[2];
    const float* as0 = (const float*)d_in[3];
    const float* ad0 = (const float*)d_in[4];
    const float* b0  = (const float*)d_in[5];
    const float* W1  = (const float*)d_in[6];
    const float* as1 = (const float*)d_in[7];
    const float* ad1 = (const float*)d_in[8];
    const float* b1  = (const float*)d_in[9];
    const float* W2  = (const float*)d_in[10];
    const float* as2 = (const float*)d_in[11];
    const float* ad2 = (const float*)d_in[12];
    const float* b2  = (const float*)d_in[13];
    float* outp = (float*)d_out;

    size_t off = 0;
    auto alloc = [&](size_t bytes) -> void* {
        void* p = (char*)d_ws + off;
        off += (bytes + 255) & ~(size_t)255;
        return p;
    };
    int*   deg    = (int*)alloc((size_t)NNODE * 4);
    int*   fill   = (int*)alloc((size_t)NNODE * 4);
    int*   rowptr = (int*)alloc((size_t)(NNODE + 1) * 4);
    int*   bsum   = (int*)alloc(256 * 4);
    int*   csr    = (int*)alloc((size_t)ETOT * 4);
    float* asrc   = (float*)alloc((size_t)NNODE * 8 * 4);
    float* adst   = (float*)alloc((size_t)NNODE * 8 * 4);
    float* bufA   = (float*)alloc((size_t)NNODE * 64 * 4);
    float* bufB   = (float*)alloc((size_t)NNODE * 64 * 4);
    float* wa     = (float*)alloc(1024 * 4);
    float* w2r    = (float*)alloc((size_t)512 * NCLS * 4);
    float* g      = (float*)alloc((size_t)NNODE * 512 * 4);

    const int nb = (NNODE + 1023) / 1024;
    const int egrid = (ETOT + 255) / 256;
    const int ngrid = (NNODE + 255) / 256;
    const int wgrid = NNODE / 4;
    const int rtiles = (NNODE + 63) / 64;

    hipMemsetAsync(deg, 0, (size_t)NNODE * 4, stream);
    hipMemsetAsync(fill, 0, (size_t)NNODE * 4, stream);
    k_hist<<<egrid, 256, 0, stream>>>(ei, deg);
    k_scan1<<<nb, 256, 0, stream>>>(deg, rowptr, bsum);
    k_scan2<<<1, 256, 0, stream>>>(bsum, nb);
    k_scan3<<<ngrid, 256, 0, stream>>>(rowptr, bsum);
    k_scatter<<<egrid, 256, 0, stream>>>(ei, rowptr, fill, csr);

    k_gemm<<<dim3(rtiles, 1), 256, 0, stream>>>(x, W0, bufA, NNODE, FIN, HID);
    k_alpha_hs<<<wgrid, 256, 0, stream>>>(bufA, as0, ad0, asrc, adst);
    k_agg64<<<wgrid, 256, 0, stream>>>(bufA, asrc, adst, rowptr, csr, b0, bufB, 1);

    k_gemm<<<dim3(rtiles, 1), 256, 0, stream>>>(bufB, W1, bufA, NNODE, HID, HID);
    k_alpha_hs<<<wgrid, 256, 0, stream>>>(bufA, as1, ad1, asrc, adst);
    k_agg64<<<wgrid, 256, 0, stream>>>(bufA, asrc, adst, rowptr, csr, b1, bufB, 1);

    k_prep_w2<<<80, 256, 0, stream>>>(W2, as2, ad2, wa, w2r);
    k_alpha2<<<wgrid, 256, 0, stream>>>(bufB, wa, asrc, adst);
    k_agg512<<<wgrid, 256, 0, stream>>>(bufB, asrc, adst, rowptr, csr, g);
    k_gemm<<<dim3(rtiles, 1), 256, 0, stream>>>(g, w2r, outp, NNODE, 512, NCLS);
    k_logsm<<<wgrid, 256, 0, stream>>>(outp, b2);
}